// Round 1
// 341.983 us; speedup vs baseline: 1.0062x; 1.0062x over previous
//
#include <hip/hip_runtime.h>
#include <hip/hip_cooperative_groups.h>

namespace cg = cooperative_groups;

#define C_CH  128
#define NP    32768
#define K_PWL 20
#define LAT   8
#define HID   8
#define SLOTS 32
#define PTS   4          // legacy pass1 points/thread
#define NBLK  512        // fused: persistent blocks (2 per CU on 256-CU MI355X)
#define TN    64         // fused: n-points per block tile (NBLK*TN == NP)

__device__ __forceinline__ float fast_tanh(float x) {
    float e = __expf(2.0f * x);
    return fmaf(-2.0f, __builtin_amdgcn_rcpf(e + 1.0f), 1.0f);
}

// monotone float<->uint encoding for atomic min/max on floats (legacy path)
__device__ __forceinline__ unsigned fenc(float f) {
    unsigned u = __float_as_uint(f);
    return (u & 0x80000000u) ? ~u : (u | 0x80000000u);
}
__device__ __forceinline__ float fdec(unsigned e) {
    unsigned u = (e & 0x80000000u) ? (e ^ 0x80000000u) : ~e;
    return __uint_as_float(u);
}

// 8->8(tanh)->1(tanh) MLP; W layout: W1[64], b1[8]@64, W2[8]@72, b2@80.
// Identical op order to the verified kernel -> identical numerics.
__device__ __forceinline__ float mlp_eval(const float* W, float4 r0, float4 r1) {
    float acc = W[80];
    #pragma unroll
    for (int j = 0; j < HID; j++) {
        float hh = W[64 + j];
        hh = fmaf(r0.x, W[0 * 8 + j], hh);
        hh = fmaf(r0.y, W[1 * 8 + j], hh);
        hh = fmaf(r0.z, W[2 * 8 + j], hh);
        hh = fmaf(r0.w, W[3 * 8 + j], hh);
        hh = fmaf(r1.x, W[4 * 8 + j], hh);
        hh = fmaf(r1.y, W[5 * 8 + j], hh);
        hh = fmaf(r1.z, W[6 * 8 + j], hh);
        hh = fmaf(r1.w, W[7 * 8 + j], hh);
        acc = fmaf(fast_tanh(hh), W[72 + j], acc);
    }
    return fast_tanh(acc);
}

// ============================ FUSED COOPERATIVE KERNEL =====================
// 512 blocks x 256 threads, 2 blocks/CU (LDS 76.2 KB/block). Each block owns
// a [128 c x 64 n] tile held in LDS across two grid syncs:
//   phase1: MLP x/e (loads pipelined 2 groups ahead) -> LDS, block partials
//   sync; phase2a: blocks 0..127 reduce per-channel min/max, block 128 sums
//   sync; phase2b: normalize + PWL + e-standardize, transposed store
__global__ __launch_bounds__(256, 2)
void fused(const float* __restrict__ zf, const float* __restrict__ zx,
           const float* __restrict__ ze,
           const float* __restrict__ Wx1, const float* __restrict__ bx1,
           const float* __restrict__ Wx2, const float* __restrict__ bx2,
           const float* __restrict__ We1, const float* __restrict__ be1,
           const float* __restrict__ We2, const float* __restrict__ be2,
           const float* __restrict__ Wf1, const float* __restrict__ bf1,
           const float* __restrict__ Wf2, const float* __restrict__ bf2,
           const unsigned char* __restrict__ dirs_raw,
           float* __restrict__ out,
           double* __restrict__ psum,   // [NBLK][2]
           float* __restrict__ pmin,    // [NBLK][128]
           float* __restrict__ pmax,    // [NBLK][128]
           float* __restrict__ gmm,     // [256] = min[128], max[128]
           float* __restrict__ gstat) { // [2] = mean, 0.1/std
    __shared__ float sx[C_CH * (TN + 1)]; // pad 65: conflict-free transpose read
    __shared__ float se[C_CH * TN];
    __shared__ float syp[C_CH * K_PWL];
    __shared__ float sw[162];
    __shared__ float smin[C_CH], sinv[C_CH];
    __shared__ float sstat2[2];
    __shared__ float rf[8];
    __shared__ double rsd[8];
    __shared__ int is_i32;

    int t = threadIdx.x;
    int b = blockIdx.x;
    int w = t >> 6, lane = t & 63;

    // ---- stage x/e MLP weights to LDS (same layout as verified kernel) ----
    if (t < 64)        sw[t] = Wx1[t];
    else if (t < 72)   sw[t] = bx1[t - 64];
    else if (t < 80)   sw[t] = Wx2[t - 72];
    else if (t == 80)  sw[80] = bx2[0];
    else if (t < 145)  sw[t] = We1[t - 81];
    else if (t < 153)  sw[t] = be1[t - 145];
    else if (t < 161)  sw[t] = We2[t - 153];
    else if (t == 161) sw[161] = be2[0];
    if (t == 192) {   // bool-storage sniff (int32 words vs uint8 bytes)
        const int* di = (const int*)dirs_raw;
        int ok = 1;
        for (int i = 0; i < 32; i++) { int v = di[i]; if (v != 0 && v != 1) ok = 0; }
        is_i32 = ok;
    }
    __syncthreads();

    // ---- phase 1: per i, wave w computes channel c=i*4+w, n = n0+lane ----
    int n0 = b * TN;
    const float4* zx4 = (const float4*)zx + ((size_t)w * NP + n0 + lane) * 2;
    const float4* ze4 = (const float4*)ze + ((size_t)w * NP + n0 + lane) * 2;
    const size_t STEP = (size_t)4 * NP * 2;  // 4 channels per i, float4 units

    float ssum = 0.f, ss2 = 0.f;
    // depth-2 software pipeline: 8 dwordx4 in flight covers ~900cy HBM latency
    float4 A0 = zx4[0], A1 = zx4[1], AE0 = ze4[0], AE1 = ze4[1];
    float4 B0 = zx4[STEP], B1 = zx4[STEP + 1], BE0 = ze4[STEP], BE1 = ze4[STEP + 1];
    #pragma unroll 2
    for (int i = 0; i < 32; i++) {
        float4 C0, C1, CE0, CE1;
        if (i + 2 < 32) {
            size_t o = (size_t)(i + 2) * STEP;
            C0 = zx4[o]; C1 = zx4[o + 1]; CE0 = ze4[o]; CE1 = ze4[o + 1];
        } else { C0 = B0; C1 = B1; CE0 = BE0; CE1 = BE1; }
        float xv = mlp_eval(sw, A0, A1);
        float ev = mlp_eval(sw + 81, AE0, AE1);
        int idx = i * 256 + t;                 // idx>>6 == channel c
        sx[idx + (idx >> 6)] = xv;             // row c padded to 65
        se[idx] = ev;
        ssum += ev;
        ss2 = fmaf(ev, ev, ss2);
        A0 = B0; A1 = B1; AE0 = BE0; AE1 = BE1;
        B0 = C0; B1 = C1; BE0 = CE0; BE1 = CE1;
    }

    // block-level e-sums (float within block -> double partial, as before)
    #pragma unroll
    for (int o = 32; o > 0; o >>= 1) {
        ssum += __shfl_down(ssum, o);
        ss2  += __shfl_down(ss2, o);
    }
    if (lane == 0) { rf[w] = ssum; rf[4 + w] = ss2; }
    __syncthreads();   // sx/se complete; rf complete

    if (t < C_CH) {
        // per-channel min/max sweep from LDS (stride-65: conflict-free)
        float mn = 3.0e38f, mx = -3.0e38f;
        int base = t * (TN + 1);
        #pragma unroll 8
        for (int j = 0; j < TN; j++) {
            float v = sx[base + j];
            mn = fminf(mn, v); mx = fmaxf(mx, v);
        }
        pmin[b * C_CH + t] = mn;
        pmax[b * C_CH + t] = mx;
        if (t == 0) {
            double S  = (double)rf[0] + (double)rf[1] + (double)rf[2] + (double)rf[3];
            double S2 = (double)rf[4] + (double)rf[5] + (double)rf[6] + (double)rf[7];
            psum[2 * b] = S; psum[2 * b + 1] = S2;
        }
    } else {
        // upper half-block: redundant per-block yp generation (overlapped).
        // Odd-even transposition sorting network: static indices -> registers.
        int c = t - 128;
        float z[LAT];
        #pragma unroll
        for (int l = 0; l < LAT; l++) z[l] = zf[c * LAT + l];
        float h[HID];
        #pragma unroll
        for (int j = 0; j < HID; j++) {
            float a = bf1[j];
            #pragma unroll
            for (int l = 0; l < LAT; l++) a = fmaf(z[l], Wf1[l * HID + j], a);
            h[j] = fast_tanh(a);
        }
        float p[K_PWL];
        #pragma unroll
        for (int k = 0; k < K_PWL; k++) {
            float a = bf2[k];
            #pragma unroll
            for (int j = 0; j < HID; j++) a = fmaf(h[j], Wf2[j * K_PWL + k], a);
            p[k] = fast_tanh(a);
        }
        #pragma unroll
        for (int ph = 0; ph < K_PWL; ph++) {
            #pragma unroll
            for (int k = (ph & 1); k + 1 < K_PWL; k += 2) {
                float lo = fminf(p[k], p[k + 1]);
                float hi = fmaxf(p[k], p[k + 1]);
                p[k] = lo; p[k + 1] = hi;
            }
        }
        int dir = is_i32 ? (((const int*)dirs_raw)[c] != 0) : (dirs_raw[c] != 0);
        #pragma unroll
        for (int k = 0; k < K_PWL; k++)
            syp[c * K_PWL + k] = dir ? p[k] : p[K_PWL - 1 - k];
    }

    __threadfence();
    cg::grid_group grid = cg::this_grid();
    grid.sync();

    // ---- phase 2a: tree reduce partials (blocks 0..127: minmax, 128: sums)
    if (b < C_CH) {
        const volatile float* vmin = pmin;
        const volatile float* vmax = pmax;
        float mn = fminf(vmin[(size_t)t * C_CH + b], vmin[(size_t)(t + 256) * C_CH + b]);
        float mx = fmaxf(vmax[(size_t)t * C_CH + b], vmax[(size_t)(t + 256) * C_CH + b]);
        #pragma unroll
        for (int o = 32; o > 0; o >>= 1) {
            mn = fminf(mn, __shfl_down(mn, o));
            mx = fmaxf(mx, __shfl_down(mx, o));
        }
        if (lane == 0) { rf[w] = mn; rf[4 + w] = mx; }
        __syncthreads();
        if (t == 0) {
            mn = fminf(fminf(rf[0], rf[1]), fminf(rf[2], rf[3]));
            mx = fmaxf(fmaxf(rf[4], rf[5]), fmaxf(rf[6], rf[7]));
            gmm[b] = mn; gmm[C_CH + b] = mx;
        }
    } else if (b == C_CH) {
        const volatile double* vs = psum;
        double S  = vs[2 * t]     + vs[2 * (t + 256)];
        double S2 = vs[2 * t + 1] + vs[2 * (t + 256) + 1];
        #pragma unroll
        for (int o = 32; o > 0; o >>= 1) {
            S  += __shfl_down(S, o);
            S2 += __shfl_down(S2, o);
        }
        if (lane == 0) { rsd[w] = S; rsd[4 + w] = S2; }
        __syncthreads();
        if (t == 0) {
            S  = rsd[0] + rsd[1] + rsd[2] + rsd[3];
            S2 = rsd[4] + rsd[5] + rsd[6] + rsd[7];
            double M = (double)C_CH * NP;
            double mean = S / M;
            double var = (S2 - S * S / M) / (M - 1.0);
            gstat[0] = (float)mean;
            gstat[1] = (float)(0.1 / sqrt(var));
        }
    }
    __threadfence();
    grid.sync();

    // ---- phase 2b: finish in LDS, transposed coalesced store ----
    if (t < C_CH) {
        const volatile float* g = gmm;
        float mn = g[t], mx = g[C_CH + t];
        smin[t] = mn;
        sinv[t] = __builtin_amdgcn_rcpf(mx - mn);
    }
    if (t == 0) {
        const volatile float* gs = gstat;
        sstat2[0] = gs[0]; sstat2[1] = gs[1];
    }
    __syncthreads();

    const float INV_DENOM = 1.0f / (1.0f / 19.0f + 1e-7f);
    float mean = sstat2[0], escale = sstat2[1];
    #pragma unroll 4
    for (int i = 0; i < 32; i++) {
        int idx = i * 256 + t;
        int c = idx >> 6;
        float x = sx[idx + c];
        float e = se[idx];
        float xn = (x - smin[c]) * sinv[c];
        int seg = (int)floorf(xn * 19.0f);
        seg = max(0, min(18, seg));
        float y0 = syp[c * K_PWL + seg];
        float y1 = syp[c * K_PWL + seg + 1];
        float y = fmaf((xn - (float)seg * (1.0f / 19.0f)) * INV_DENOM, y1 - y0, y0);
        y = fmaf(e - mean, escale, y);
        sx[idx + c] = y;   // in-place: each slot touched by exactly one thread
    }
    __syncthreads();
    #pragma unroll 4
    for (int ii = 0; ii < 32; ii++) {
        int idx2 = ii * 256 + t;
        int c = idx2 & 127;        // lanes -> consecutive c: coalesced store
        int j = idx2 >> 7;
        out[(size_t)(n0 + j) * C_CH + c] = sx[c * (TN + 1) + j];
    }
}

// ============================ LEGACY FALLBACK PATH =========================
__global__ void prep(const float* __restrict__ zf,
                     const float* __restrict__ Wf1, const float* __restrict__ bf1,
                     const float* __restrict__ Wf2, const float* __restrict__ bf2,
                     const unsigned char* __restrict__ dirs_raw,
                     float* __restrict__ ypw,
                     unsigned* cminE, unsigned* cmaxE, double* sums) {
    int t = threadIdx.x;
    if (t < C_CH) { cminE[t] = 0xFFFFFFFFu; cmaxE[t] = 0u; }
    if (t < 2 * SLOTS) sums[t] = 0.0;

    __shared__ int is_i32;
    if (t == 0) {
        const int* di = (const int*)dirs_raw;
        int ok = 1;
        for (int i = 0; i < 32; i++) { int v = di[i]; if (v != 0 && v != 1) ok = 0; }
        is_i32 = ok;
    }
    __syncthreads();
    if (t >= C_CH) return;
    int c = t;

    float z[LAT];
    #pragma unroll
    for (int l = 0; l < LAT; l++) z[l] = zf[c * LAT + l];
    float h[HID];
    #pragma unroll
    for (int j = 0; j < HID; j++) {
        float a = bf1[j];
        #pragma unroll
        for (int l = 0; l < LAT; l++) a = fmaf(z[l], Wf1[l * HID + j], a);
        h[j] = fast_tanh(a);
    }
    float p[K_PWL];
    #pragma unroll
    for (int k = 0; k < K_PWL; k++) {
        float a = bf2[k];
        #pragma unroll
        for (int j = 0; j < HID; j++) a = fmaf(h[j], Wf2[j * K_PWL + k], a);
        p[k] = fast_tanh(a);
    }
    for (int i = 1; i < K_PWL; i++) {
        float key = p[i];
        int j = i - 1;
        while (j >= 0 && p[j] > key) { p[j + 1] = p[j]; j--; }
        p[j + 1] = key;
    }
    int dir = is_i32 ? (((const int*)dirs_raw)[c] != 0) : (dirs_raw[c] != 0);
    for (int k = 0; k < K_PWL; k++)
        ypw[c * K_PWL + k] = dir ? p[k] : p[K_PWL - 1 - k];
}

__global__ __launch_bounds__(256)
void pass1(const float* __restrict__ zx, const float* __restrict__ ze,
           const float* __restrict__ Wx1, const float* __restrict__ bx1,
           const float* __restrict__ Wx2, const float* __restrict__ bx2,
           const float* __restrict__ We1, const float* __restrict__ be1,
           const float* __restrict__ We2, const float* __restrict__ be2,
           float* __restrict__ xraw, float* __restrict__ eraw,
           unsigned* __restrict__ cminE, unsigned* __restrict__ cmaxE,
           double* __restrict__ sums) {
    __shared__ float sw[162];
    int t = threadIdx.x;
    if (t < 64)       sw[t] = Wx1[t];
    else if (t < 72)  sw[t] = bx1[t - 64];
    else if (t < 80)  sw[t] = Wx2[t - 72];
    else if (t == 80) sw[80] = bx2[0];
    else if (t < 145) sw[t] = We1[t - 81];
    else if (t < 153) sw[t] = be1[t - 145];
    else if (t < 161) sw[t] = We2[t - 153];
    else if (t == 161) sw[161] = be2[0];
    __syncthreads();

    int c = blockIdx.y;
    int n0 = blockIdx.x * (256 * PTS) + t;
    size_t row = (size_t)c * NP;
    const float4* zx4 = (const float4*)(zx + row * LAT);
    const float4* ze4 = (const float4*)(ze + row * LAT);

    float4 ax[PTS][2], ae[PTS][2];
    #pragma unroll
    for (int k = 0; k < PTS; k++) {
        int n = n0 + k * 256;
        ax[k][0] = zx4[2 * n];  ax[k][1] = zx4[2 * n + 1];
        ae[k][0] = ze4[2 * n];  ae[k][1] = ze4[2 * n + 1];
    }

    float xv[PTS], ev[PTS];
    #pragma unroll
    for (int k = 0; k < PTS; k++) xv[k] = mlp_eval(sw, ax[k][0], ax[k][1]);
    #pragma unroll
    for (int k = 0; k < PTS; k++) ev[k] = mlp_eval(sw + 81, ae[k][0], ae[k][1]);

    float mn = xv[0], mx = xv[0], s = 0.f, s2 = 0.f;
    #pragma unroll
    for (int k = 0; k < PTS; k++) {
        xraw[row + n0 + k * 256] = xv[k];
        eraw[row + n0 + k * 256] = ev[k];
        mn = fminf(mn, xv[k]); mx = fmaxf(mx, xv[k]);
        s += ev[k]; s2 += ev[k] * ev[k];
    }

    #pragma unroll
    for (int o = 32; o > 0; o >>= 1) {
        mn = fminf(mn, __shfl_down(mn, o));
        mx = fmaxf(mx, __shfl_down(mx, o));
        s += __shfl_down(s, o);
        s2 += __shfl_down(s2, o);
    }
    __shared__ float rmn[4], rmx[4], rs[4], rs2[4];
    int wave = t >> 6, lane = t & 63;
    if (lane == 0) { rmn[wave] = mn; rmx[wave] = mx; rs[wave] = s; rs2[wave] = s2; }
    __syncthreads();
    if (t == 0) {
        for (int w = 1; w < 4; w++) {
            mn = fminf(mn, rmn[w]); mx = fmaxf(mx, rmx[w]);
            s += rs[w]; s2 += rs2[w];
        }
        atomicMin(&cminE[c], fenc(mn));
        atomicMax(&cmaxE[c], fenc(mx));
        int slot = (blockIdx.x + blockIdx.y) & (SLOTS - 1);
        atomicAdd(&sums[2 * slot], (double)s);
        atomicAdd(&sums[2 * slot + 1], (double)s2);
    }
}

__global__ __launch_bounds__(256)
void pass2(const float* __restrict__ xraw, const float* __restrict__ eraw,
           const float* __restrict__ ypw,
           const unsigned* __restrict__ cminE, const unsigned* __restrict__ cmaxE,
           const double* __restrict__ sums,
           float* __restrict__ out) {
    __shared__ float ytile[C_CH * 33];
    __shared__ float syp[C_CH * K_PWL];
    __shared__ float smin[C_CH], sinv[C_CH];
    __shared__ float sstat[2];

    int t = threadIdx.x;
    for (int i = t; i < C_CH * K_PWL; i += 256) syp[i] = ypw[i];
    if (t < C_CH) {
        float mn = fdec(cminE[t]);
        float mx = fdec(cmaxE[t]);
        smin[t] = mn;
        sinv[t] = __builtin_amdgcn_rcpf(mx - mn);
    }
    if (t == 0) {
        double s = 0.0, s2 = 0.0;
        for (int i = 0; i < SLOTS; i++) { s += sums[2 * i]; s2 += sums[2 * i + 1]; }
        double M = (double)C_CH * NP;
        double mean = s / M;
        double var = (s2 - s * s / M) / (M - 1.0);
        sstat[0] = (float)mean;
        sstat[1] = (float)(0.1 / sqrt(var));
    }
    __syncthreads();

    const float INV_DENOM = 1.0f / (1.0f / 19.0f + 1e-7f);
    float mean = sstat[0], escale = sstat[1];
    int n0 = blockIdx.x * 32;

    #pragma unroll
    for (int i = 0; i < 16; i++) {
        int idx = i * 256 + t;
        int c = idx >> 5;
        int j = idx & 31;
        size_t g = (size_t)c * NP + (n0 + j);
        float x = xraw[g];
        float e = eraw[g];
        float xn = (x - smin[c]) * sinv[c];
        int seg = (int)floorf(xn * 19.0f);
        seg = max(0, min(18, seg));
        float y0 = syp[c * K_PWL + seg];
        float y1 = syp[c * K_PWL + seg + 1];
        float y = fmaf((xn - (float)seg * (1.0f / 19.0f)) * INV_DENOM, y1 - y0, y0);
        y = fmaf(e - mean, escale, y);
        ytile[c * 33 + j] = y;
    }
    __syncthreads();
    #pragma unroll
    for (int i = 0; i < 16; i++) {
        int idx = i * 256 + t;
        int j = idx >> 7;
        int c = idx & 127;
        out[(size_t)(n0 + j) * C_CH + c] = ytile[c * 33 + j];
    }
}

extern "C" void kernel_launch(void* const* d_in, const int* in_sizes, int n_in,
                              void* d_out, int out_size, void* d_ws, size_t ws_size,
                              hipStream_t stream) {
    const float* zf  = (const float*)d_in[0];
    const float* zx  = (const float*)d_in[1];
    const float* ze  = (const float*)d_in[2];
    const float* Wx1 = (const float*)d_in[3];
    const float* bx1 = (const float*)d_in[4];
    const float* Wx2 = (const float*)d_in[5];
    const float* bx2 = (const float*)d_in[6];
    const float* We1 = (const float*)d_in[7];
    const float* be1 = (const float*)d_in[8];
    const float* We2 = (const float*)d_in[9];
    const float* be2 = (const float*)d_in[10];
    const float* Wf1 = (const float*)d_in[11];
    const float* bf1 = (const float*)d_in[12];
    const float* Wf2 = (const float*)d_in[13];
    const float* bf2 = (const float*)d_in[14];
    const unsigned char* dirs = (const unsigned char*)d_in[15];
    float* outp = (float*)d_out;

    // mode: 1 = fused cooperative (needs 2 blocks/CU co-residency), 0 = legacy
    static int mode = -1;
    if (mode < 0) {
        int dev = 0, coop = 0, nb = 0;
        hipGetDevice(&dev);
        hipDeviceGetAttribute(&coop, hipDeviceAttributeCooperativeLaunch, dev);
        hipError_t oe = hipOccupancyMaxActiveBlocksPerMultiprocessor(
            &nb, reinterpret_cast<const void*>(fused), 256, 0);
        mode = (coop && oe == hipSuccess && nb >= 2) ? 1 : 0;
    }

    if (mode == 1) {
        double* psum  = (double*)d_ws;                  // NBLK*2 doubles (8 KB)
        float*  pmin  = (float*)(psum + 2 * NBLK);      // NBLK*128
        float*  pmax  = pmin + NBLK * C_CH;             // NBLK*128
        float*  gmm   = pmax + NBLK * C_CH;             // 256
        float*  gstat = gmm + 2 * C_CH;                 // 2   (total ~528 KB)
        void* args[] = {
            (void*)&zf,  (void*)&zx,  (void*)&ze,
            (void*)&Wx1, (void*)&bx1, (void*)&Wx2, (void*)&bx2,
            (void*)&We1, (void*)&be1, (void*)&We2, (void*)&be2,
            (void*)&Wf1, (void*)&bf1, (void*)&Wf2, (void*)&bf2,
            (void*)&dirs, (void*)&outp,
            (void*)&psum, (void*)&pmin, (void*)&pmax, (void*)&gmm, (void*)&gstat
        };
        hipError_t le = hipLaunchCooperativeKernel(
            reinterpret_cast<const void*>(fused), dim3(NBLK), dim3(256),
            args, 0, stream);
        if (le == hipSuccess) return;
        mode = 0;   // cooperative launch rejected -> permanent legacy fallback
    }

    // legacy 3-kernel path (verified baseline)
    float* xraw = (float*)d_ws;
    float* eraw = xraw + (size_t)C_CH * NP;
    float* ypw  = eraw + (size_t)C_CH * NP;
    unsigned* cminE = (unsigned*)(ypw + C_CH * K_PWL);
    unsigned* cmaxE = cminE + C_CH;
    double* sums = (double*)(cmaxE + C_CH);

    hipLaunchKernelGGL(prep, dim3(1), dim3(256), 0, stream,
                       zf, Wf1, bf1, Wf2, bf2, dirs, ypw, cminE, cmaxE, sums);
    hipLaunchKernelGGL(pass1, dim3(NP / (256 * PTS), C_CH), dim3(256), 0, stream,
                       zx, ze, Wx1, bx1, Wx2, bx2, We1, be1, We2, be2,
                       xraw, eraw, cminE, cmaxE, sums);
    hipLaunchKernelGGL(pass2, dim3(NP / 32), dim3(256), 0, stream,
                       xraw, eraw, ypw, cminE, cmaxE, sums, outp);
}